// Round 9
// baseline (100.489 us; speedup 1.0000x reference)
//
#include <hip/hip_runtime.h>
#include <hip/hip_bf16.h>

#define N_NODES 8192
#define IN_F 128
#define OUT_F 64
#define ALPHA 0.2f
#define CAPB 1024      // per-row edge cap (expected ~164, max ~230)
#define WT_STRIDE 132  // 16B-aligned lane rows for ds_read_b128

typedef __attribute__((ext_vector_type(4))) float f32x4;

// Kernel 1: h = x @ W  [N,64];  hi = h @ a[:64];  hj = h @ a[64:]
__global__ __launch_bounds__(256, 4) void gat_h(
    const float* __restrict__ x, const float* __restrict__ W,
    const float* __restrict__ a, float* __restrict__ h,
    float* __restrict__ hi, float* __restrict__ hj) {
  __shared__ float sWt[OUT_F][WT_STRIDE];  // sWt[f][k] = W[k][f]
  int tid = threadIdx.x;
  for (int i = tid; i < IN_F * OUT_F; i += 256) {
    int k = i >> 6, f = i & 63;
    sWt[f][k] = W[i];
  }
  __syncthreads();

  int lane = tid & 63;
  int wid = tid >> 6;
  float a1 = a[lane], a2 = a[OUT_F + lane];
  int row0 = blockIdx.x * 8;

  for (int rr = 0; rr < 2; ++rr) {
    int row = row0 + rr * 4 + wid;
    const float4* xr = (const float4*)(x + (size_t)row * IN_F);
    float acc = 0.f;
#pragma unroll
    for (int k4 = 0; k4 < IN_F / 4; ++k4) {
      float4 xv = xr[k4];
      float4 wv = *(const float4*)&sWt[lane][k4 * 4];
      acc = fmaf(xv.x, wv.x, acc);
      acc = fmaf(xv.y, wv.y, acc);
      acc = fmaf(xv.z, wv.z, acc);
      acc = fmaf(xv.w, wv.w, acc);
    }
    h[(size_t)row * 64 + lane] = acc;
    float vi = acc * a1, vj = acc * a2;
#pragma unroll
    for (int o = 32; o >= 1; o >>= 1) {
      vi += __shfl_xor(vi, o);
      vj += __shfl_xor(vj, o);
    }
    if (lane == 0) { hi[row] = vi; hj[row] = vj; }
  }
}

// Kernel 2: block-per-row (R3 structure), improved:
//  - 8 adj loads pinned in flight via asm barrier (R3 had VGPR=12, serialized)
//  - exp fused into placement (no separate exp pass; no-max softmax, |l|<~10)
//  - no LDS atomic: wave totals + one barrier
//  - 8-accumulator gather, block-interleaved (wave w: 8-edge chunks, stride 32)
__global__ __launch_bounds__(256, 4) void gat_row(
    const float* __restrict__ adj, const float* __restrict__ h,
    const float* __restrict__ hi, const float* __restrict__ hj,
    float* __restrict__ out) {
  __shared__ int s_idx[CAPB + 32];
  __shared__ float s_w[CAPB + 32];
  __shared__ int s_tot[4];
  __shared__ float s_psum[4];
  __shared__ float s_part[4][64];

  int tid = threadIdx.x;
  int lane = tid & 63;
  int wid = tid >> 6;
  int row = blockIdx.x;

  // --- scan: 8 float4/thread, all 8 issued before any use ---
  const f32x4* arow = (const f32x4*)(adj + (size_t)row * N_NODES);
  f32x4 v0 = arow[tid];
  f32x4 v1 = arow[tid + 256];
  f32x4 v2 = arow[tid + 512];
  f32x4 v3 = arow[tid + 768];
  f32x4 v4 = arow[tid + 1024];
  f32x4 v5 = arow[tid + 1280];
  f32x4 v6 = arow[tid + 1536];
  f32x4 v7 = arow[tid + 1792];
  asm volatile("" : "+v"(v0), "+v"(v1), "+v"(v2), "+v"(v3),
                    "+v"(v4), "+v"(v5), "+v"(v6), "+v"(v7));

  unsigned int mk = 0;
#define MASK4(v, it)                                   \
  mk |= (unsigned int)(v.x > 0.f) << (it * 4 + 0);     \
  mk |= (unsigned int)(v.y > 0.f) << (it * 4 + 1);     \
  mk |= (unsigned int)(v.z > 0.f) << (it * 4 + 2);     \
  mk |= (unsigned int)(v.w > 0.f) << (it * 4 + 3);
  MASK4(v0, 0) MASK4(v1, 1) MASK4(v2, 2) MASK4(v3, 3)
  MASK4(v4, 4) MASK4(v5, 5) MASK4(v6, 6) MASK4(v7, 7)
#undef MASK4
  int c = __popc(mk);

  // --- wave prefix + wave totals (no atomic) ---
  int incl = c;
#pragma unroll
  for (int o = 1; o < 64; o <<= 1) {
    int t = __shfl_up(incl, o);
    if (lane >= o) incl += t;
  }
  if (lane == 63) s_tot[wid] = incl;
  __syncthreads();  // B1: wave totals visible
  int t0 = s_tot[0], t1 = s_tot[1], t2 = s_tot[2], t3 = s_tot[3];
  int base = (wid > 0 ? t0 : 0) + (wid > 1 ? t1 : 0) + (wid > 2 ? t2 : 0);
  int off = base + incl - c;
  int cnt = t0 + t1 + t2 + t3;
  if (cnt > CAPB) cnt = CAPB;
  int cnp = (cnt + 31) & ~31;

  // --- placement: leaky-relu -> exp fused, shared list, psum ---
  float hii = hi[row];
  float psum = 0.f;
  while (mk) {
    int b = __ffs(mk) - 1;  // bit = it*4 + comp; float4 idx = tid + it*256
    mk &= mk - 1;
    int j = (tid << 2) + ((b >> 2) << 10) + (b & 3);
    float l = hii + hj[j];
    l = (l > 0.f) ? l : ALPHA * l;
    float w = __expf(l);
    if (off < CAPB) { s_idx[off] = j; s_w[off] = w; }
    ++off;
    psum += w;
  }
  for (int e = cnt + tid; e < cnp; e += 256) { s_w[e] = 0.f; s_idx[e] = 0; }
#pragma unroll
  for (int o = 32; o >= 1; o >>= 1) psum += __shfl_xor(psum, o);
  if (lane == 0) s_psum[wid] = psum;
  __syncthreads();  // B2: placement + pad + psums visible
  float inv = 1.f / (s_psum[0] + s_psum[1] + s_psum[2] + s_psum[3]);

  // --- gather: 8 accumulators, wave-interleaved 8-edge chunks ---
  float acc0 = 0.f, acc1 = 0.f, acc2 = 0.f, acc3 = 0.f;
  float acc4 = 0.f, acc5 = 0.f, acc6 = 0.f, acc7 = 0.f;
  for (int e = wid * 8; e < cnp; e += 32) {
    int4 ia = *(const int4*)&s_idx[e];
    int4 ib = *(const int4*)&s_idx[e + 4];
    float4 wa = *(const float4*)&s_w[e];
    float4 wb = *(const float4*)&s_w[e + 4];
    acc0 = fmaf(wa.x, h[(size_t)ia.x * 64 + lane], acc0);
    acc1 = fmaf(wa.y, h[(size_t)ia.y * 64 + lane], acc1);
    acc2 = fmaf(wa.z, h[(size_t)ia.z * 64 + lane], acc2);
    acc3 = fmaf(wa.w, h[(size_t)ia.w * 64 + lane], acc3);
    acc4 = fmaf(wb.x, h[(size_t)ib.x * 64 + lane], acc4);
    acc5 = fmaf(wb.y, h[(size_t)ib.y * 64 + lane], acc5);
    acc6 = fmaf(wb.z, h[(size_t)ib.z * 64 + lane], acc6);
    acc7 = fmaf(wb.w, h[(size_t)ib.w * 64 + lane], acc7);
  }
  s_part[wid][lane] =
      ((acc0 + acc1) + (acc2 + acc3)) + ((acc4 + acc5) + (acc6 + acc7));
  __syncthreads();  // B3: partials visible
  if (tid < 64) {
    float vv = s_part[0][tid] + s_part[1][tid] + s_part[2][tid] + s_part[3][tid];
    vv *= inv;
    vv = (vv > 0.f) ? vv : expm1f(vv);  // ELU
    out[(size_t)row * 64 + tid] = vv;
  }
}

extern "C" void kernel_launch(void* const* d_in, const int* in_sizes, int n_in,
                              void* d_out, int out_size, void* d_ws, size_t ws_size,
                              hipStream_t stream) {
  const float* x   = (const float*)d_in[0];  // [8192,128]
  const float* adj = (const float*)d_in[1];  // [8192,8192]
  const float* W   = (const float*)d_in[2];  // [128,64]
  const float* a   = (const float*)d_in[3];  // [128,1]
  float* out = (float*)d_out;                // [8192,64]

  float* h  = (float*)d_ws;                  // 8192*64
  float* hi = h + (size_t)N_NODES * OUT_F;   // 8192
  float* hj = hi + N_NODES;                  // 8192

  gat_h<<<N_NODES / 8, 256, 0, stream>>>(x, W, a, h, hi, hj);
  gat_row<<<N_NODES, 256, 0, stream>>>(adj, h, hi, hj, out);
}

// Round 10
// 97.711 us; speedup vs baseline: 1.0284x; 1.0284x over previous
//
#include <hip/hip_runtime.h>
#include <hip/hip_bf16.h>

#define N_NODES 8192
#define IN_F 128
#define OUT_F 64
#define ALPHA 0.2f
#define CAPB 1024      // per-row edge cap (expected ~164, max ~230)
#define WT_STRIDE 132  // 16B-aligned lane rows for ds_read_b128

// Kernel 1: h = x @ W  [N,64];  hi = h @ a[:64];  hj = h @ a[64:]
__global__ __launch_bounds__(256, 4) void gat_h(
    const float* __restrict__ x, const float* __restrict__ W,
    const float* __restrict__ a, float* __restrict__ h,
    float* __restrict__ hi, float* __restrict__ hj) {
  __shared__ float sWt[OUT_F][WT_STRIDE];  // sWt[f][k] = W[k][f]
  int tid = threadIdx.x;
  for (int i = tid; i < IN_F * OUT_F; i += 256) {
    int k = i >> 6, f = i & 63;
    sWt[f][k] = W[i];
  }
  __syncthreads();

  int lane = tid & 63;
  int wid = tid >> 6;
  float a1 = a[lane], a2 = a[OUT_F + lane];
  int row0 = blockIdx.x * 8;

  for (int rr = 0; rr < 2; ++rr) {
    int row = row0 + rr * 4 + wid;
    const float4* xr = (const float4*)(x + (size_t)row * IN_F);
    float acc = 0.f;
#pragma unroll
    for (int k4 = 0; k4 < IN_F / 4; ++k4) {
      float4 xv = xr[k4];
      float4 wv = *(const float4*)&sWt[lane][k4 * 4];
      acc = fmaf(xv.x, wv.x, acc);
      acc = fmaf(xv.y, wv.y, acc);
      acc = fmaf(xv.z, wv.z, acc);
      acc = fmaf(xv.w, wv.w, acc);
    }
    h[(size_t)row * 64 + lane] = acc;
    float vi = acc * a1, vj = acc * a2;
#pragma unroll
    for (int o = 32; o >= 1; o >>= 1) {
      vi += __shfl_xor(vi, o);
      vj += __shfl_xor(vj, o);
    }
    if (lane == 0) { hi[row] = vi; hj[row] = vj; }
  }
}

// Kernel 2: R3's block-per-row structure (VGPR~12, max occupancy — the
// proven-fast variant), with the hj gather moved OUT of the divergent
// placement loop into a flat parallel pass, no-max exp, 8-acc gather.
__global__ __launch_bounds__(256) void gat_row(
    const float* __restrict__ adj, const float* __restrict__ h,
    const float* __restrict__ hi, const float* __restrict__ hj,
    float* __restrict__ out) {
  __shared__ int s_idx[CAPB + 32];
  __shared__ float s_w[CAPB + 32];
  __shared__ int s_cnt;
  __shared__ float s_psum[4];
  __shared__ float s_part[4][64];

  int tid = threadIdx.x;
  int lane = tid & 63;
  int wid = tid >> 6;
  int row = blockIdx.x;

  if (tid == 0) s_cnt = 0;

  // --- scan: 8 float4/thread, sequential mask build (low VGPR, rely on TLP) ---
  const float4* arow = (const float4*)(adj + (size_t)row * N_NODES);
  unsigned int mk = 0;
#pragma unroll
  for (int it = 0; it < 8; ++it) {
    float4 vv = arow[tid + it * 256];
    mk |= (unsigned int)(vv.x > 0.f) << (it * 4 + 0);
    mk |= (unsigned int)(vv.y > 0.f) << (it * 4 + 1);
    mk |= (unsigned int)(vv.z > 0.f) << (it * 4 + 2);
    mk |= (unsigned int)(vv.w > 0.f) << (it * 4 + 3);
  }
  int c = __popc(mk);

  // --- wave prefix ---
  int incl = c;
#pragma unroll
  for (int o = 1; o < 64; o <<= 1) {
    int t = __shfl_up(incl, o);
    if (lane >= o) incl += t;
  }

  __syncthreads();  // B0: s_cnt = 0 visible
  int base = 0;
  if (lane == 63) base = atomicAdd(&s_cnt, incl);
  base = __shfl(base, 63);
  int off = base + incl - c;

  // --- placement: indices ONLY (pure int ops in the divergent loop) ---
  while (mk) {
    int b = __ffs(mk) - 1;  // bit = it*4 + comp; float4 idx = tid + it*256
    mk &= mk - 1;
    int j = (tid << 2) + ((b >> 2) << 10) + (b & 3);
    if (off < CAPB) s_idx[off] = j;
    ++off;
  }
  __syncthreads();  // B1: s_idx + s_cnt final
  int cnt = s_cnt;
  if (cnt > CAPB) cnt = CAPB;
  int cnp = (cnt + 31) & ~31;

  // --- flat parallel pass: hj gather + leaky-relu + exp + psum ---
  // (164 independent L2 gathers in flight block-wide, no serial chain)
  float hii = hi[row];
  float psum = 0.f;
  for (int e = tid; e < cnt; e += 256) {
    int j = s_idx[e];
    float l = hii + hj[j];
    l = (l > 0.f) ? l : ALPHA * l;
    float w = __expf(l);  // no max-sub: |l| <= ~12, fp32-safe (validated R7/R8)
    s_w[e] = w;
    psum += w;
  }
  for (int e = cnt + tid; e < cnp; e += 256) { s_w[e] = 0.f; s_idx[e] = 0; }
#pragma unroll
  for (int o = 32; o >= 1; o >>= 1) psum += __shfl_xor(psum, o);
  if (lane == 0) s_psum[wid] = psum;
  __syncthreads();  // B2: s_w + pad + psums visible
  float inv = 1.f / (s_psum[0] + s_psum[1] + s_psum[2] + s_psum[3]);

  // --- gather: 8 accumulators, wave-interleaved 8-edge chunks ---
  float acc0 = 0.f, acc1 = 0.f, acc2 = 0.f, acc3 = 0.f;
  float acc4 = 0.f, acc5 = 0.f, acc6 = 0.f, acc7 = 0.f;
  for (int e = wid * 8; e < cnp; e += 32) {
    int4 ia = *(const int4*)&s_idx[e];
    int4 ib = *(const int4*)&s_idx[e + 4];
    float4 wa = *(const float4*)&s_w[e];
    float4 wb = *(const float4*)&s_w[e + 4];
    acc0 = fmaf(wa.x, h[(size_t)ia.x * 64 + lane], acc0);
    acc1 = fmaf(wa.y, h[(size_t)ia.y * 64 + lane], acc1);
    acc2 = fmaf(wa.z, h[(size_t)ia.z * 64 + lane], acc2);
    acc3 = fmaf(wa.w, h[(size_t)ia.w * 64 + lane], acc3);
    acc4 = fmaf(wb.x, h[(size_t)ib.x * 64 + lane], acc4);
    acc5 = fmaf(wb.y, h[(size_t)ib.y * 64 + lane], acc5);
    acc6 = fmaf(wb.z, h[(size_t)ib.z * 64 + lane], acc6);
    acc7 = fmaf(wb.w, h[(size_t)ib.w * 64 + lane], acc7);
  }
  s_part[wid][lane] =
      ((acc0 + acc1) + (acc2 + acc3)) + ((acc4 + acc5) + (acc6 + acc7));
  __syncthreads();  // B3: partials visible
  if (tid < 64) {
    float vv = s_part[0][tid] + s_part[1][tid] + s_part[2][tid] + s_part[3][tid];
    vv *= inv;
    vv = (vv > 0.f) ? vv : expm1f(vv);  // ELU
    out[(size_t)row * 64 + tid] = vv;
  }
}

extern "C" void kernel_launch(void* const* d_in, const int* in_sizes, int n_in,
                              void* d_out, int out_size, void* d_ws, size_t ws_size,
                              hipStream_t stream) {
  const float* x   = (const float*)d_in[0];  // [8192,128]
  const float* adj = (const float*)d_in[1];  // [8192,8192]
  const float* W   = (const float*)d_in[2];  // [128,64]
  const float* a   = (const float*)d_in[3];  // [128,1]
  float* out = (float*)d_out;                // [8192,64]

  float* h  = (float*)d_ws;                  // 8192*64
  float* hi = h + (size_t)N_NODES * OUT_F;   // 8192
  float* hj = hi + N_NODES;                  // 8192

  gat_h<<<N_NODES / 8, 256, 0, stream>>>(x, W, a, h, hi, hj);
  gat_row<<<N_NODES, 256, 0, stream>>>(adj, h, hi, hj, out);
}

// Round 11
// 84.120 us; speedup vs baseline: 1.1946x; 1.1616x over previous
//
#include <hip/hip_runtime.h>
#include <hip/hip_bf16.h>

#define N_NODES 8192
#define IN_F 128
#define OUT_F 64
#define ALPHA 0.2f
#define CAP 1024  // max edges per row (expected ~164, binomial max ~230)

// Kernel 1: h = x @ W  [N,64];  hi = h @ a[:64];  hj = h @ a[64:]
__global__ __launch_bounds__(256) void gat_h(
    const float* __restrict__ x, const float* __restrict__ W,
    const float* __restrict__ a, float* __restrict__ h,
    float* __restrict__ hi, float* __restrict__ hj) {
  __shared__ float sW[IN_F * OUT_F];  // 32 KB
  int tid = threadIdx.x;
  for (int i = tid; i < IN_F * OUT_F; i += 256) sW[i] = W[i];
  __syncthreads();

  int f = tid & 63;        // output feature (lane)
  int rloc = tid >> 6;     // wave id 0..3
  float a1 = a[f], a2 = a[OUT_F + f];
  int row0 = blockIdx.x * 32;

  for (int rr = 0; rr < 8; ++rr) {
    int row = row0 + rr * 4 + rloc;
    const float4* xr = (const float4*)(x + (size_t)row * IN_F);
    float acc = 0.f;
#pragma unroll
    for (int k4 = 0; k4 < IN_F / 4; ++k4) {
      float4 xv = xr[k4];  // wave-uniform broadcast load
      acc = fmaf(xv.x, sW[(k4 * 4 + 0) * 64 + f], acc);
      acc = fmaf(xv.y, sW[(k4 * 4 + 1) * 64 + f], acc);
      acc = fmaf(xv.z, sW[(k4 * 4 + 2) * 64 + f], acc);
      acc = fmaf(xv.w, sW[(k4 * 4 + 3) * 64 + f], acc);
    }
    h[(size_t)row * 64 + f] = acc;
    float vi = acc * a1, vj = acc * a2;
#pragma unroll
    for (int o = 32; o >= 1; o >>= 1) {
      vi += __shfl_xor(vi, o);
      vj += __shfl_xor(vj, o);
    }
    if (f == 0) { hi[row] = vi; hj[row] = vj; }
  }
}

// Kernel 2: one block (256 threads) per row.
// adj row -> per-thread 32-bit edge mask (loads fully in flight, values
// discarded immediately) -> popc/prefix-sum -> ctz placement -> softmax ->
// 4-accumulator unrolled gather of h.
__global__ __launch_bounds__(256) void gat_row(
    const float* __restrict__ adj, const float* __restrict__ h,
    const float* __restrict__ hi, const float* __restrict__ hj,
    float* __restrict__ out) {
  __shared__ int s_idx[CAP + 64];
  __shared__ float s_w[CAP + 64];
  __shared__ int s_cnt;
  __shared__ float s_redA[4];
  __shared__ float s_redB[4];
  __shared__ float s_part[4][64];

  int tid = threadIdx.x;
  int lane = tid & 63;
  int wid = tid >> 6;
  int row = blockIdx.x;

  if (tid == 0) s_cnt = 0;

  // --- adj row -> 32-bit mask per thread (8 independent dwordx4 loads) ---
  const float4* arow = (const float4*)(adj + (size_t)row * N_NODES);
  unsigned int mask = 0;
#pragma unroll
  for (int it = 0; it < 8; ++it) {
    float4 vv = arow[tid + it * 256];
    mask |= (unsigned int)(vv.x > 0.f) << (it * 4 + 0);
    mask |= (unsigned int)(vv.y > 0.f) << (it * 4 + 1);
    mask |= (unsigned int)(vv.z > 0.f) << (it * 4 + 2);
    mask |= (unsigned int)(vv.w > 0.f) << (it * 4 + 3);
  }
  int c = __popc(mask);

  // --- wave inclusive prefix sum of c ---
  int incl = c;
#pragma unroll
  for (int o = 1; o < 64; o <<= 1) {
    int t = __shfl_up(incl, o);
    if (lane >= o) incl += t;
  }

  __syncthreads();  // s_cnt = 0 visible
  int base = 0;
  if (lane == 63) base = atomicAdd(&s_cnt, incl);  // one atomic per wave
  base = __shfl(base, 63);
  int off = base + incl - c;  // exclusive prefix within block

  // --- place edges via ctz, compute leaky-relu logits, local max ---
  float hii = hi[row];
  float lmax = -1e30f;
  unsigned int m = mask;
  while (m) {
    int b = __ffs(m) - 1;      // bit position 0..31
    m &= m - 1;
    // bit b = component (b&3) of float4 index (tid + (b>>2)*256)
    int j = ((tid + ((b >> 2) << 8)) << 2) + (b & 3);
    float l = hii + hj[j];
    l = (l > 0.f) ? l : ALPHA * l;
    s_w[off] = l;
    s_idx[off] = j;
    ++off;
    lmax = fmaxf(lmax, l);
  }

  // --- block max ---
#pragma unroll
  for (int o = 32; o >= 1; o >>= 1) lmax = fmaxf(lmax, __shfl_xor(lmax, o));
  if (lane == 0) s_redA[wid] = lmax;
  __syncthreads();  // placement + maxes done; s_cnt final
  float bmax = fmaxf(fmaxf(s_redA[0], s_redA[1]), fmaxf(s_redA[2], s_redA[3]));
  int cnt = s_cnt;
  int cnt_pad = (cnt + 15) & ~15;

  // --- exp + block sum; pad tail so gather needs no bounds checks ---
  float lsum = 0.f;
  for (int e = tid; e < cnt; e += 256) {
    float w = __expf(s_w[e] - bmax);
    s_w[e] = w;
    lsum += w;
  }
  for (int e = cnt + tid; e < cnt_pad; e += 256) {
    s_w[e] = 0.f;
    s_idx[e] = 0;
  }
#pragma unroll
  for (int o = 32; o >= 1; o >>= 1) lsum += __shfl_xor(lsum, o);
  if (lane == 0) s_redB[wid] = lsum;
  __syncthreads();  // s_w exp-values + padding + sums visible
  float bsum = s_redB[0] + s_redB[1] + s_redB[2] + s_redB[3];

  // --- weighted gather of h: wave-uniform quads, 4 accumulators ---
  int f = lane;
  float acc0 = 0.f, acc1 = 0.f, acc2 = 0.f, acc3 = 0.f;
  for (int e = wid * 4; e < cnt_pad; e += 16) {
    int4 id = *(const int4*)&s_idx[e];     // wave-uniform broadcast reads
    float4 wv = *(const float4*)&s_w[e];
    acc0 = fmaf(wv.x, h[(size_t)id.x * 64 + f], acc0);
    acc1 = fmaf(wv.y, h[(size_t)id.y * 64 + f], acc1);
    acc2 = fmaf(wv.z, h[(size_t)id.z * 64 + f], acc2);
    acc3 = fmaf(wv.w, h[(size_t)id.w * 64 + f], acc3);
  }
  s_part[wid][f] = (acc0 + acc1) + (acc2 + acc3);
  __syncthreads();
  if (tid < 64) {
    float vv = s_part[0][f] + s_part[1][f] + s_part[2][f] + s_part[3][f];
    vv /= bsum;
    vv = (vv > 0.f) ? vv : expm1f(vv);  // ELU
    out[(size_t)row * 64 + f] = vv;
  }
}

extern "C" void kernel_launch(void* const* d_in, const int* in_sizes, int n_in,
                              void* d_out, int out_size, void* d_ws, size_t ws_size,
                              hipStream_t stream) {
  const float* x   = (const float*)d_in[0];  // [8192,128]
  const float* adj = (const float*)d_in[1];  // [8192,8192]
  const float* W   = (const float*)d_in[2];  // [128,64]
  const float* a   = (const float*)d_in[3];  // [128,1]
  float* out = (float*)d_out;                // [8192,64]

  float* h  = (float*)d_ws;                  // 8192*64
  float* hi = h + (size_t)N_NODES * OUT_F;   // 8192
  float* hj = hi + N_NODES;                  // 8192

  gat_h<<<N_NODES / 32, 256, 0, stream>>>(x, W, a, h, hi, hj);
  gat_row<<<N_NODES, 256, 0, stream>>>(adj, h, hi, hj, out);
}